// Round 11
// baseline (1336.836 us; speedup 1.0000x reference)
//
#include <hip/hip_runtime.h>
#include <stdint.h>

// LSTM B=256,T=2048,D=U=64 fp32. 256 WGs x 256 thr, but ONLY WAVE 0 WORKS
// (waves 1-3 return; 256-thr WG keeps the 1-WG/CU dispatch mapping).
// R9 (605us) paid a cross-wave s_barrier per step for the h exchange.
// R11: ONE wave computes all 16 N-tiles (256 gate cols) itself ->
// h exchange is a wave-private LDS round trip, DS in-order, ZERO barriers
// in the t-loop. R9's acc-persistence kept: per 16-step chunk the 16 f32x4
// accs hold bias + X_chunk@Wx (rows=timesteps); step s adds h@Wh into row s
// only (A = h in row s, zeros elsewhere). Owner lane-group (l>>4 == s>>2)
// holds z for 4 units x 4 gates -> full in-lane state update, 4x b16 h
// write, 8 coalesced output stores. c migrates groups via ds_bpermute every
// 4 steps (R9-verified addresses). k-map f(g,e)=g*8+e on BOTH A and B
// (R9/R10-verified). No __syncthreads / s_barrier / waitcnt asm anywhere.

#define T_STEPS 2048
#define DIM     64
#define GATES   256
#define CHUNK   16
#define NCHUNK  (T_STEPS / CHUNK)

typedef _Float16 f16;
typedef _Float16 f16x8 __attribute__((ext_vector_type(8)));
typedef float    f32x4 __attribute__((ext_vector_type(4)));

__device__ __forceinline__ float sigm(float z) {
    return __builtin_amdgcn_rcpf(1.f + __expf(-z));
}

#define MFMA16(A, B, C) __builtin_amdgcn_mfma_f32_16x16x32_f16(A, B, C, 0, 0, 0)

__global__ __launch_bounds__(256, 1)
void lstm_sw_kernel(const float* __restrict__ x,
                    const float* __restrict__ Wx,
                    const float* __restrict__ Wh,
                    const float* __restrict__ bias,
                    float* __restrict__ out)
{
    // [0:64) h (f16) | [64:128) pad | [128:192) zeros (A rows != s)
    __shared__ __align__(16) f16 sH[192];

    const int tid = threadIdx.x;
    const int batch = blockIdx.x;
    if (tid >= 64) return;                 // single working wave

    const int l = tid;
    const int j = l & 15;                  // A-row select / D-col within tile
    const int g = l >> 4;                  // k-group: k = ks*32 + g*8 + e

    const float* xb = x + (size_t)batch * T_STEPS * DIM;
    float* ob = out + (size_t)batch * T_STEPS * (2 * DIM);

    // ---- B fragments: tile T = cols 16T..16T+15 (gate q = T>>2, unit
    // sub-block v = T&3 -> unit u = 16v + j). col = 16T + j. ----
    f16x8 Bh[16][2], Bx[16][2];
    float bv[16];
#pragma unroll
    for (int T = 0; T < 16; ++T) {
        const int col = 16 * T + j;
        bv[T] = bias[col];
#pragma unroll
        for (int ks = 0; ks < 2; ++ks)
#pragma unroll
            for (int e = 0; e < 8; ++e) {
                const int k = ks * 32 + g * 8 + e;
                Bh[T][ks][e] = (f16)Wh[k * GATES + col];
                Bx[T][ks][e] = (f16)Wx[k * GATES + col];
            }
    }

    sH[l]       = (f16)0.f;                // h0 = 0
    sH[64 + l]  = (f16)0.f;                // pad
    sH[128 + l] = (f16)0.f;                // permanent zeros

    // ---- x prefetch chunk 0: A row = ts = j, k = g*8+e / 32+g*8+e ----
    float4 x0, x1, x2, x3;
    {
        const float* xr = xb + (size_t)j * DIM + g * 8;
        x0 = *(const float4*)(xr);
        x1 = *(const float4*)(xr + 4);
        x2 = *(const float4*)(xr + 32);
        x3 = *(const float4*)(xr + 36);
    }

    // c for units {j, 16+j, 32+j, 48+j}, valid in the current owner group
    float c0 = 0.f, c1 = 0.f, c2 = 0.f, c3 = 0.f;
    const int addrMig  = ((l - 16) & 63) * 4;   // group ss-1 -> ss
    const int addrWrap = ((l + 48) & 63) * 4;   // group 3 -> 0

    f32x4 acc[16];

#pragma unroll 1
    for (int n = 0; n < NCHUNK; ++n) {
        // pack prefetched x into A frags
        f16x8 ax0, ax1;
        ax0[0]=(f16)x0.x; ax0[1]=(f16)x0.y; ax0[2]=(f16)x0.z; ax0[3]=(f16)x0.w;
        ax0[4]=(f16)x1.x; ax0[5]=(f16)x1.y; ax0[6]=(f16)x1.z; ax0[7]=(f16)x1.w;
        ax1[0]=(f16)x2.x; ax1[1]=(f16)x2.y; ax1[2]=(f16)x2.z; ax1[3]=(f16)x2.w;
        ax1[4]=(f16)x3.x; ax1[5]=(f16)x3.y; ax1[6]=(f16)x3.z; ax1[7]=(f16)x3.w;

        // acc = bias + X_chunk @ Wx  (rows = 16 timesteps)
#pragma unroll
        for (int T = 0; T < 16; ++T) {
            f32x4 a = {bv[T], bv[T], bv[T], bv[T]};
            a = MFMA16(ax0, Bx[T][0], a);
            a = MFMA16(ax1, Bx[T][1], a);
            acc[T] = a;
        }

        // prefetch next chunk's x (16-step window hides HBM latency)
        if (n + 1 < NCHUNK) {
            const float* xr = xb + ((size_t)(n + 1) * CHUNK + j) * DIM + g * 8;
            x0 = *(const float4*)(xr);
            x1 = *(const float4*)(xr + 4);
            x2 = *(const float4*)(xr + 32);
            x3 = *(const float4*)(xr + 36);
        }

#pragma unroll 1
        for (int ss = 0; ss < 4; ++ss) {
            if (ss > 0) {                  // c migrates to new owner group
                c0 = __int_as_float(__builtin_amdgcn_ds_bpermute(addrMig, __float_as_int(c0)));
                c1 = __int_as_float(__builtin_amdgcn_ds_bpermute(addrMig, __float_as_int(c1)));
                c2 = __int_as_float(__builtin_amdgcn_ds_bpermute(addrMig, __float_as_int(c2)));
                c3 = __int_as_float(__builtin_amdgcn_ds_bpermute(addrMig, __float_as_int(c3)));
            }
#pragma unroll
            for (int r = 0; r < 4; ++r) {
                const int s = ss * 4 + r;
                // A = h_{t-1} in row s, zeros elsewhere
                const int aoff = (j == s) ? (g * 8) : (128 + g * 8);
                f16x8 A0 = *(const f16x8*)&sH[aoff];
                f16x8 A1 = *(const f16x8*)&sH[aoff + 32];
#pragma unroll
                for (int T = 0; T < 16; ++T) {
                    acc[T] = MFMA16(A0, Bh[T][0], acc[T]);
                    acc[T] = MFMA16(A1, Bh[T][1], acc[T]);
                }
                // state update (meaningful in owner group g==ss; others garbage)
                float hh0, hh1, hh2, hh3;
                {   float gi = sigm(acc[0][r]),  gf = sigm(acc[4][r]);
                    float go = sigm(acc[12][r]);
                    float gg = fmaf(2.f, sigm(acc[8][r] + acc[8][r]), -1.f);
                    c0 = fmaf(gf, c0, gi * gg);
                    float e2 = __expf(-2.f * fabsf(c0));
                    float th = copysignf(fmaf(-2.f, e2 * __builtin_amdgcn_rcpf(1.f + e2), 1.f), c0);
                    hh0 = go * th; }
                {   float gi = sigm(acc[1][r]),  gf = sigm(acc[5][r]);
                    float go = sigm(acc[13][r]);
                    float gg = fmaf(2.f, sigm(acc[9][r] + acc[9][r]), -1.f);
                    c1 = fmaf(gf, c1, gi * gg);
                    float e2 = __expf(-2.f * fabsf(c1));
                    float th = copysignf(fmaf(-2.f, e2 * __builtin_amdgcn_rcpf(1.f + e2), 1.f), c1);
                    hh1 = go * th; }
                {   float gi = sigm(acc[2][r]),  gf = sigm(acc[6][r]);
                    float go = sigm(acc[14][r]);
                    float gg = fmaf(2.f, sigm(acc[10][r] + acc[10][r]), -1.f);
                    c2 = fmaf(gf, c2, gi * gg);
                    float e2 = __expf(-2.f * fabsf(c2));
                    float th = copysignf(fmaf(-2.f, e2 * __builtin_amdgcn_rcpf(1.f + e2), 1.f), c2);
                    hh2 = go * th; }
                {   float gi = sigm(acc[3][r]),  gf = sigm(acc[7][r]);
                    float go = sigm(acc[15][r]);
                    float gg = fmaf(2.f, sigm(acc[11][r] + acc[11][r]), -1.f);
                    c3 = fmaf(gf, c3, gi * gg);
                    float e2 = __expf(-2.f * fabsf(c3));
                    float th = copysignf(fmaf(-2.f, e2 * __builtin_amdgcn_rcpf(1.f + e2), 1.f), c3);
                    hh3 = go * th; }

                if (g == ss) {             // owner publishes h + stores output
                    sH[ 0 + j] = (f16)hh0;
                    sH[16 + j] = (f16)hh1;
                    sH[32 + j] = (f16)hh2;
                    sH[48 + j] = (f16)hh3;
                    const size_t t = (size_t)n * CHUNK + s;
                    float* oc = ob + t * 128;
                    oc[      j] = c0;  oc[16 + j] = c1;
                    oc[32 + j] = c2;  oc[48 + j] = c3;
                    oc[64 + j] = hh0; oc[80 + j] = hh1;
                    oc[96 + j] = hh2; oc[112 + j] = hh3;
                }
            }
        }
        // chunk wrap: c moves group 3 -> 0
        c0 = __int_as_float(__builtin_amdgcn_ds_bpermute(addrWrap, __float_as_int(c0)));
        c1 = __int_as_float(__builtin_amdgcn_ds_bpermute(addrWrap, __float_as_int(c1)));
        c2 = __int_as_float(__builtin_amdgcn_ds_bpermute(addrWrap, __float_as_int(c2)));
        c3 = __int_as_float(__builtin_amdgcn_ds_bpermute(addrWrap, __float_as_int(c3)));
    }
}

extern "C" void kernel_launch(void* const* d_in, const int* in_sizes, int n_in,
                              void* d_out, int out_size, void* d_ws, size_t ws_size,
                              hipStream_t stream) {
    const float* x  = (const float*)d_in[0];
    const float* Wx = (const float*)d_in[1];
    const float* Wh = (const float*)d_in[2];
    const float* b  = (const float*)d_in[3];
    float* out = (float*)d_out;

    hipLaunchKernelGGL(lstm_sw_kernel, dim3(256), dim3(256), 0, stream,
                       x, Wx, Wh, b, out);
}

// Round 13
// 586.143 us; speedup vs baseline: 2.2807x; 2.2807x over previous
//
#include <hip/hip_runtime.h>
#include <stdint.h>

// LSTM B=256,T=2048,D=U=64 fp32. 256 WGs (1 batch) x 256 thr (4 waves).
// R13 = R10 skeleton (grid 256, replay-proven sync) + R12's zero-C h-MFMA:
//  - replicated-A (all 16 rows = h): z lands in EVERY lane -> no bpermute,
//    no owner migration, no conditional A row (R9's latency terms gone).
//  - h.Wh accumulates into a register with PERSISTENT zero C-init -> no
//    per-step accvgpr re-init (R10's regression term gone).
//  - xz = bias + X_chunk @ Wx per 16-step chunk via MFMA (rows=timesteps),
//    scattered once to wave-private LDS; per-step read = one b128 bcast;
//    z_q = hreg_q[0] + xz_q (scalar add).
//  One lgkm-only barrier per step (cross-wave h exchange); vmcnt never
//  drained. k-map f(g,e)=g*8+e on BOTH A and B; C/D layout m89-verified.

#define T_STEPS 2048
#define DIM     64
#define GATES   256
#define CHUNK   16
#define NCHUNK  (T_STEPS / CHUNK)

typedef _Float16 f16;
typedef _Float16 f16x8 __attribute__((ext_vector_type(8)));
typedef float    f32x4 __attribute__((ext_vector_type(4)));

__device__ __forceinline__ void sync_lds() {
    __builtin_amdgcn_sched_barrier(0);
    asm volatile("s_waitcnt lgkmcnt(0)" ::: "memory");
    __builtin_amdgcn_sched_barrier(0);
    __builtin_amdgcn_s_barrier();
    __builtin_amdgcn_sched_barrier(0);
}

__device__ __forceinline__ float sigm(float z) {
    return __builtin_amdgcn_rcpf(1.f + __expf(-z));
}

#define MFMA16(A, B, C) __builtin_amdgcn_mfma_f32_16x16x32_f16(A, B, C, 0, 0, 0)

__device__ __forceinline__ void pack8(f16x8& d, const float4& a, const float4& b) {
    d[0]=(f16)a.x; d[1]=(f16)a.y; d[2]=(f16)a.z; d[3]=(f16)a.w;
    d[4]=(f16)b.x; d[5]=(f16)b.y; d[6]=(f16)b.z; d[7]=(f16)b.w;
}

__global__ __launch_bounds__(256, 1)
void lstm_r13_kernel(const float* __restrict__ x,
                     const float* __restrict__ Wx,
                     const float* __restrict__ Wh,
                     const float* __restrict__ bias,
                     float* __restrict__ out)
{
    __shared__ __align__(16) f16   sH[2][64];             // h dbuf (f16)
    __shared__ __align__(16) float sXZ[4][CHUNK][16][4];  // wave-private xz

    const int tid  = threadIdx.x;
    const int lane = tid & 63;
    const int w    = tid >> 6;       // wave 0..3 -> units w*16..+16
    const int j    = lane & 15;      // col-in-tile (B,D) / row (A, xz MFMA)
    const int g    = lane >> 4;      // k-group: k = ks*32 + g*8 + e
    const int u    = w * 16 + j;     // unit

    const int batch = blockIdx.x;
    const float* xb = x + (size_t)batch * T_STEPS * DIM;
    float* ob = out + (size_t)batch * T_STEPS * (2 * DIM);

    // ---- persistent B fragments: col = q*64 + u, k = ks*32 + g*8 + e ----
    f16x8 Bh[4][2], Bx[4][2];
    f32x4 bias4[4];
#pragma unroll
    for (int q = 0; q < 4; ++q) {
        const int col = q * 64 + u;
        const float bb = bias[col];
        bias4[q][0] = bb; bias4[q][1] = bb; bias4[q][2] = bb; bias4[q][3] = bb;
#pragma unroll
        for (int ks = 0; ks < 2; ++ks)
#pragma unroll
            for (int e = 0; e < 8; ++e) {
                const int k = ks * 32 + g * 8 + e;
                Bh[q][ks][e] = (f16)Wh[k * GATES + col];
                Bx[q][ks][e] = (f16)Wx[k * GATES + col];
            }
    }
    const f32x4 zero4 = {0.f, 0.f, 0.f, 0.f};

    if (tid < 128) sH[tid >> 6][tid & 63] = (f16)0.f;

    // ---- prefetch x chunk 0: A row = ts = j, feats g*8.. ----
    float4 x0, x1, x2, x3;
    {
        const float* xr = xb + (size_t)j * DIM + g * 8;
        x0 = *(const float4*)(xr);      x1 = *(const float4*)(xr + 4);
        x2 = *(const float4*)(xr + 32); x3 = *(const float4*)(xr + 36);
    }

    float c = 0.f;   // replicated: every lane-group's lane j holds c[u]
    __syncthreads();

#pragma unroll 1
    for (int n = 0; n < NCHUNK; ++n) {
        // ---- xz chunk: z[q] = bias + X_chunk @ Wx (rows = 16 ts) ----
        f16x8 ax0, ax1;
        pack8(ax0, x0, x1); pack8(ax1, x2, x3);
        f32x4 z0 = MFMA16(ax0, Bx[0][0], bias4[0]); z0 = MFMA16(ax1, Bx[0][1], z0);
        f32x4 z1 = MFMA16(ax0, Bx[1][0], bias4[1]); z1 = MFMA16(ax1, Bx[1][1], z1);
        f32x4 z2 = MFMA16(ax0, Bx[2][0], bias4[2]); z2 = MFMA16(ax1, Bx[2][1], z2);
        f32x4 z3 = MFMA16(ax0, Bx[3][0], bias4[3]); z3 = MFMA16(ax1, Bx[3][1], z3);
        // scatter to wave-private sXZ: row = 4g+r (D-layout), unit j
#pragma unroll
        for (int r = 0; r < 4; ++r) {
            float4 v = {z0[r], z1[r], z2[r], z3[r]};
            *(float4*)&sXZ[w][4 * g + r][j][0] = v;
        }
        asm volatile("s_waitcnt lgkmcnt(0)" ::: "memory");  // wave-private

        // prefetch next chunk's x (returns during the 16 steps below)
        if (n + 1 < NCHUNK) {
            const float* xr = xb + ((size_t)(n + 1) * CHUNK + j) * DIM + g * 8;
            x0 = *(const float4*)(xr);      x1 = *(const float4*)(xr + 4);
            x2 = *(const float4*)(xr + 32); x3 = *(const float4*)(xr + 36);
        }

#pragma unroll
        for (int s = 0; s < CHUNK; ++s) {
            const int pb = s & 1;
            // xz for this step (broadcast b128, off critical path)
            float4 xzv = *(const float4*)&sXZ[w][s][j][0];
            // A = h replicated in all rows (read depends only on g)
            f16x8 A0 = *(const f16x8*)&sH[pb][g * 8];
            f16x8 A1 = *(const f16x8*)&sH[pb][32 + g * 8];

            f32x4 h0 = MFMA16(A0, Bh[0][0], zero4); h0 = MFMA16(A1, Bh[0][1], h0);
            f32x4 h1 = MFMA16(A0, Bh[1][0], zero4); h1 = MFMA16(A1, Bh[1][1], h1);
            f32x4 h2 = MFMA16(A0, Bh[2][0], zero4); h2 = MFMA16(A1, Bh[2][1], h2);
            f32x4 h3 = MFMA16(A0, Bh[3][0], zero4); h3 = MFMA16(A1, Bh[3][1], h3);

            float zi = h0[0] + xzv.x, zf = h1[0] + xzv.y;
            float zg = h2[0] + xzv.z, zo = h3[0] + xzv.w;
            float gi = sigm(zi), gf = sigm(zf), go = sigm(zo);
            float gg = fmaf(2.f, sigm(zg + zg), -1.f);
            c = fmaf(gf, c, gi * gg);
            float e2 = __expf(-2.f * fabsf(c));
            float th = copysignf(
                fmaf(-2.f, e2 * __builtin_amdgcn_rcpf(1.f + e2), 1.f), c);
            float hh = go * th;

            const size_t t = (size_t)n * CHUNK + s;
            if (g == 2)      sH[pb ^ 1][u] = (f16)hh;     // next-step h
            else if (g == 0) ob[t * 128 + u]      = c;    // cell out
            else if (g == 1) ob[t * 128 + 64 + u] = hh;   // hidden out
            sync_lds();
        }
    }
}

extern "C" void kernel_launch(void* const* d_in, const int* in_sizes, int n_in,
                              void* d_out, int out_size, void* d_ws, size_t ws_size,
                              hipStream_t stream) {
    const float* x  = (const float*)d_in[0];
    const float* Wx = (const float*)d_in[1];
    const float* Wh = (const float*)d_in[2];
    const float* b  = (const float*)d_in[3];
    float* out = (float*)d_out;

    hipLaunchKernelGGL(lstm_r13_kernel, dim3(256), dim3(256), 0, stream,
                       x, Wx, Wh, b, out);
}